// Round 3
// baseline (267.846 us; speedup 1.0000x reference)
//
#include <hip/hip_runtime.h>

// GraphSAGE: 3x (project -> mean-aggregate) + mean pool + log_softmax.
// R20: full linear collapse. The network has NO nonlinearity, and the mean-
//      aggregation operator S commutes with feature transforms: S(H)M = S(HM).
//      So:  q2 = S(x@A) + x@B + c1   (A = Wl1Wl2Wt, B = Wr1Wl2Wt, 128x20)
//           r  = S(x@C) + x@D + c2   (C = Wl1Wr2Wt, D = Wr1Wr2Wt)
//      Pipeline: prep (bucket scatter + tiny on-chip matrix chain -> Wq,cbv)
//        -> fillX (CSR fill + one N x 128 x 80 MFMA GEMM -> mm bf16 / bmrow f32)
//        -> aggM (20+20-dim gather over 80B rows; mm = 3.8MiB fits per-XCD L2)
//        -> agg20 -> agg10_pool -> finalize (all unchanged).
//      Replaces the E x 128B fp8 gather (49us, 59MB FETCH) and the 256-wide
//      layer-1 GEMM. 6 dispatches.

#define CAP 48
#define EB 4096

typedef __attribute__((ext_vector_type(8))) short short8;
typedef __attribute__((ext_vector_type(4))) float floatx4;

static __device__ __forceinline__ unsigned short f2bf(float f) {
    unsigned int u = __float_as_uint(f);
    u += 0x7FFFu + ((u >> 16) & 1u);
    return (unsigned short)(u >> 16);
}
static __device__ __forceinline__ float bf2f(unsigned short b) {
    return __uint_as_float(((unsigned int)b) << 16);
}

// ---------------- prep: bucket scatter + combined-matrix chain + zeroing ----
// Combined matrices (all on-chip, one block):
//   wt[c][f]  : c<10 -> Wl3[f][c], c>=10 -> Wr3[f][c-10]          (20x128)
//   m2[k][c]  = sum_f Wl2[k][f] wt[c][f]                          (128x20)
//   m2r[k][c] = sum_f Wr2[k][f] wt[c][f]                          (128x20)
//   P[k][f80] : f<20 -> Wl1.m2 (m1) | 20..39 -> Wl1.m2r (m1r)
//               40..59 -> Wr1.m2 (bm) | 60..79 -> Wr1.m2r (bmr)
//   Wq = bf16 MFMA-packed P (5 m-tiles x 4 k-steps x 64 lanes x 8)
//   cbv[0..19]  = bl1 @ m2
//   cbv[20..39] = bl1 @ m2r + bl2 @ wt
__global__ void prep_weights(const float* __restrict__ Wl1, const float* __restrict__ Wr1,
                             const float* __restrict__ Wl2, const float* __restrict__ Wr2,
                             const float* __restrict__ Wl3, const float* __restrict__ Wr3,
                             const float* __restrict__ bl1, const float* __restrict__ bl2,
                             short* __restrict__ Wq, float* __restrict__ cbv,
                             int* __restrict__ zero_base, int zero_words,
                             unsigned int* __restrict__ mmz, unsigned int* __restrict__ q2b32,
                             unsigned int* __restrict__ t3b32, int N,
                             const int* __restrict__ ei, int E, int ablk, int nbk,
                             unsigned int* __restrict__ bedges, int* __restrict__ runCnt) {
    __shared__ int hist[512];
    __shared__ float wt_s[20 * 128];
    __shared__ float m2_s[128 * 20];
    __shared__ float m2r_s[128 * 20];
    if (blockIdx.x < (unsigned)ablk) {
        for (int i = threadIdx.x; i < nbk; i += 256) hist[i] = 0;
        __syncthreads();
        int e0 = blockIdx.x * EB + threadIdx.x;
        unsigned int pk[16];
        int bk[16], loc[16];
#pragma unroll
        for (int k = 0; k < 16; ++k) {
            int e = e0 + k * 256;
            if (e < E) {
                int src = ei[e];
                int dst = ei[E + e];
                bk[k] = dst >> 7;
                pk[k] = ((unsigned int)(dst & 127) << 16) | (unsigned int)src;
                loc[k] = atomicAdd(&hist[bk[k]], 1);    // LDS atomic
            } else bk[k] = -1;
        }
        __syncthreads();
        for (int i = threadIdx.x; i < nbk; i += 256)
            runCnt[(size_t)blockIdx.x * nbk + i] = hist[i];
#pragma unroll
        for (int k = 0; k < 16; ++k)
            if (bk[k] >= 0 && loc[k] < CAP)
                bedges[((size_t)bk[k] * ablk + blockIdx.x) * CAP + loc[k]] = pk[k];
        return;
    }
    int rb = blockIdx.x - ablk;
    if (rb == 0) {
        const int tid = threadIdx.x;
        // stage 1: wt
        for (int i = tid; i < 2560; i += 256) {
            int c = i >> 7, f = i & 127;
            wt_s[i] = (c < 10) ? Wl3[f * 10 + c] : Wr3[f * 10 + (c - 10)];
        }
        __syncthreads();
        // stage 2: m2 / m2r
        for (int idx = tid; idx < 2560; idx += 256) {
            int k = idx / 20, c = idx - k * 20;
            const float* w2l = Wl2 + (size_t)k * 128;
            const float* w2r = Wr2 + (size_t)k * 128;
            const float* wc = wt_s + c * 128;
            float s1 = 0.f, s2 = 0.f;
            for (int f = 0; f < 128; ++f) { s1 += w2l[f] * wc[f]; s2 += w2r[f] * wc[f]; }
            m2_s[k * 20 + c] = s1;
            m2r_s[k * 20 + c] = s2;
        }
        __syncthreads();
        // stage 3: P entries, packed straight into global Wq (bf16, MFMA layout)
        for (int idx = tid; idx < 10240; idx += 256) {
            int k = idx / 80, f = idx - k * 80;
            const float* wrow = ((f < 40) ? Wl1 : Wr1) + (size_t)k * 128;
            const float* mcol = ((f / 20) & 1) ? m2r_s : m2_s;
            int c = f % 20;
            float s = 0.f;
            for (int j = 0; j < 128; ++j) s += wrow[j] * mcol[j * 20 + c];
            // pack: k = ks*32 + q*8 + jj ; f = mi*16 + m ; lane l = q*16+m
            int ks = k >> 5, rem = k & 31, q = rem >> 3, jj = rem & 7;
            int mi = f >> 4, m = f & 15;
            int l = q * 16 + m;
            Wq[(((mi * 4 + ks) * 64) + l) * 8 + jj] = (short)f2bf(s);
        }
        // stage 4: cbv (reads m2/m2r/wt, stable since stage-2 sync)
        if (tid < 40) {
            float s = 0.f;
            if (tid < 20) {
                for (int k = 0; k < 128; ++k) s += bl1[k] * m2_s[k * 20 + tid];
            } else {
                int c = tid - 20;
                for (int k = 0; k < 128; ++k) s += bl1[k] * m2r_s[k * 20 + c];
                for (int f = 0; f < 128; ++f) s += bl2[f] * wt_s[c * 128 + f];
            }
            cbv[tid] = s;
        }
        return;
    }
    if (rb == 1) {
        // zero rows: mm (20 uints), q2b (10), t3b (10)
        if (threadIdx.x < 20) mmz[(size_t)N * 20 + threadIdx.x] = 0;
        if (threadIdx.x >= 32 && threadIdx.x < 42)
            q2b32[(size_t)N * 10 + (threadIdx.x - 32)] = 0;
        if (threadIdx.x >= 64 && threadIdx.x < 74)
            t3b32[(size_t)N * 10 + (threadIdx.x - 64)] = 0;
        return;
    }
    int i = (rb - 2) * 256 + threadIdx.x;
    if (i < zero_words) zero_base[i] = 0;
}

// ---------------- fillX: phase-B CSR fill + dense x @ [A|C|B|D] ----------------
// Projection blocks: 64 nodes/block, wave w owns nodes node0+w*16+m, computes
// all 80 outputs (5 m-tiles). f<40 -> mm row [m1(20)|m1r(20)] bf16 (80B);
// f>=40 -> bmrow row [bm(20)|bmr(20)] fp32 (+cbv consts).
__global__ __launch_bounds__(256) void fillX(
    const float* __restrict__ x, const short* __restrict__ Wq,
    const float* __restrict__ cbv, unsigned short* __restrict__ mm,
    float* __restrict__ bmrow, int N, int nbk, int ablk,
    const unsigned int* __restrict__ bedges, const int* __restrict__ runCnt,
    int* __restrict__ cnt, unsigned short* __restrict__ colbuf) {
    __shared__ unsigned short As[64 * 136];
    __shared__ int lcnt[128];
    if (blockIdx.x >= (unsigned)nbk) {
        int blk = blockIdx.x - nbk;
        int node0 = blk * 64;
#pragma unroll
        for (int c = 0; c < 8; ++c) {
            int idx = c * 256 + threadIdx.x;
            int r = idx >> 5;
            int c4 = idx & 31;
            int row = node0 + r;
            float4 v = make_float4(0.f, 0.f, 0.f, 0.f);
            if (row < N) v = *(const float4*)&x[(size_t)row * 128 + c4 * 4];
            ushort4 p;
            p.x = f2bf(v.x); p.y = f2bf(v.y); p.z = f2bf(v.z); p.w = f2bf(v.w);
            *(ushort4*)&As[r * 136 + c4 * 4] = p;
        }
        __syncthreads();

        const int w = threadIdx.x >> 6;
        const int lane = threadIdx.x & 63;
        const int q = lane >> 4;
        const int m = lane & 15;

        floatx4 acc[5] = {};
#pragma unroll
        for (int s = 0; s < 4; ++s) {
            short8 bfrag = *(const short8*)&As[(w * 16 + m) * 136 + s * 32 + q * 8];
#pragma unroll
            for (int mi = 0; mi < 5; ++mi) {
                short8 wf = *(const short8*)&Wq[((mi * 4 + s) * 64 + lane) * 8];
                acc[mi] = __builtin_amdgcn_mfma_f32_16x16x32_bf16(
                    wf, bfrag, acc[mi], 0, 0, 0);
            }
        }
        int node = node0 + w * 16 + m;
        if (node < N) {
#pragma unroll
            for (int mi = 0; mi < 5; ++mi) {
                int f0 = mi * 16 + q * 4;
                floatx4 a = acc[mi];
                if (f0 < 40) {
                    ushort4 p;
                    p.x = f2bf(a[0]); p.y = f2bf(a[1]);
                    p.z = f2bf(a[2]); p.w = f2bf(a[3]);
                    *(ushort4*)&mm[(size_t)node * 40 + f0] = p;
                } else {
                    float4 cb = *(const float4*)&cbv[f0 - 40];
                    float4 o = make_float4(a[0] + cb.x, a[1] + cb.y,
                                           a[2] + cb.z, a[3] + cb.w);
                    *(float4*)&bmrow[(size_t)node * 40 + (f0 - 40)] = o;
                }
            }
        }
    } else {
        int b = blockIdx.x;
        if (threadIdx.x < 128) lcnt[threadIdx.x] = 0;
        __syncthreads();
        for (int blk = threadIdx.x; blk < ablk; blk += 256) {
            int c = runCnt[(size_t)blk * nbk + b];
            c = min(c, CAP);
            size_t ebase = ((size_t)b * ablk + blk) * CAP;
            for (int i = 0; i < c; ++i) {
                unsigned int pk = bedges[ebase + i];
                int dl = pk >> 16;
                int slot = atomicAdd(&lcnt[dl], 1);    // LDS atomic
                if (slot < CAP)
                    colbuf[(size_t)(b * 128 + dl) * CAP + slot] =
                        (unsigned short)(pk & 0xFFFFu);
            }
        }
        __syncthreads();
        int node = b * 128 + threadIdx.x;
        if (threadIdx.x < 128 && node < N) cnt[node] = lcnt[threadIdx.x];
    }
}

// ---------------- aggM: 40-dim gather over mm (80B rows, L2-resident) --------
// q2[n] = mean_s m1[s] + bm[n]  (bf16 out);  rvec[n] = mean_s m1r[s] + bmr[n].
__global__ __launch_bounds__(256) void aggM(
    const uint2* __restrict__ mm2, const int* __restrict__ cnt,
    const unsigned short* __restrict__ colbuf, const float* __restrict__ bmrow,
    unsigned short* __restrict__ q2b, float* __restrict__ rbuf, int N) {
    const int lane = threadIdx.x & 63;
    const int wvi = threadIdx.x >> 6;
    const int la = lane & 15;
    const int qb = lane & 48;
    const int node = blockIdx.x * 16 + wvi * 4 + (lane >> 4);
    const bool valid = node < N;
    const int nodec = valid ? node : N - 1;
    const int deg = cnt[nodec];
    const int d = valid ? min(deg, CAP) : 0;
    const unsigned short* cb = colbuf + (size_t)nodec * CAP;

    float f0 = 0.f, f1 = 0.f, f2 = 0.f, f3 = 0.f;
    int nb = (d + 15) >> 4;
    for (int b = 0; b < nb; ++b) {
        int slot = b * 16 + la;
        int idx = (slot < d) ? (int)cb[slot] : N;   // N = mm zero row
        uint2 vv[16];
#pragma unroll
        for (int j = 0; j < 16; ++j) {
            int s = __shfl(idx, qb + j, 64);
            uint2 z; z.x = 0u; z.y = 0u;
            vv[j] = (la < 10) ? mm2[(size_t)s * 10 + la] : z;
        }
#pragma unroll
        for (int j = 0; j < 16; ++j) {
            f0 += bf2f((unsigned short)(vv[j].x & 0xFFFF));
            f1 += bf2f((unsigned short)(vv[j].x >> 16));
            f2 += bf2f((unsigned short)(vv[j].y & 0xFFFF));
            f3 += bf2f((unsigned short)(vv[j].y >> 16));
        }
    }
    if (valid && la < 10) {
        float inv = 1.0f / (float)max(deg, 1);
        float4 bv = *(const float4*)&bmrow[(size_t)node * 40 + la * 4];
        float o0 = f0 * inv + bv.x, o1 = f1 * inv + bv.y;
        float o2 = f2 * inv + bv.z, o3 = f3 * inv + bv.w;
        if (la < 5) {
            ushort4 p;
            p.x = f2bf(o0); p.y = f2bf(o1); p.z = f2bf(o2); p.w = f2bf(o3);
            *(ushort4*)&q2b[(size_t)node * 20 + la * 4] = p;
        } else {
            *(float4*)&rbuf[(size_t)node * 20 + (la - 5) * 4] =
                make_float4(o0, o1, o2, o3);
        }
    }
}

// ---------------- layer-2 aggregate (20-dim q2) + t3 assembly ----------------
// t3[n] cols 0..9 = mean_s q2_l[s] + r_l[n] + bl3 (biased trick),
//       cols 10..19 = mean_s q2_r[s] + r_r[n].  Stored bf16 (40B rows).
__global__ __launch_bounds__(256) void agg20(
    const unsigned int* __restrict__ q2b32, const int* __restrict__ cnt,
    const unsigned short* __restrict__ colbuf, const float2* __restrict__ rbuf2,
    const float* __restrict__ bl3, unsigned int* __restrict__ t3b32, int N) {
    const int lane = threadIdx.x & 63;
    const int wvi = threadIdx.x >> 6;
    const int la = lane & 15;
    const int qb = lane & 48;
    const int node = blockIdx.x * 16 + wvi * 4 + (lane >> 4);
    const bool valid = node < N;
    const int nodec = valid ? node : N - 1;
    const int deg = cnt[nodec];
    const int d = valid ? min(deg, CAP) : 0;
    const unsigned short* cb = colbuf + (size_t)nodec * CAP;

    float f0 = 0.f, f1 = 0.f;
    int nb = (d + 15) >> 4;
    for (int b = 0; b < nb; ++b) {
        int slot = b * 16 + la;
        int idx = (slot < d) ? (int)cb[slot] : N;   // N = q2 zero row
        unsigned int vv[16];
#pragma unroll
        for (int j = 0; j < 16; ++j) {
            int s = __shfl(idx, qb + j, 64);
            vv[j] = (la < 10) ? q2b32[(size_t)s * 10 + la] : 0u;
        }
#pragma unroll
        for (int j = 0; j < 16; ++j) {
            f0 += bf2f((unsigned short)(vv[j] & 0xFFFF));
            f1 += bf2f((unsigned short)(vv[j] >> 16));
        }
    }
    if (valid && la < 10) {
        float inv = 1.0f / (float)max(deg, 1);
        float2 rv = rbuf2[(size_t)node * 10 + la];
        float v0 = f0 * inv + rv.x;
        float v1 = f1 * inv + rv.y;
        if (la < 5) { v0 += bl3[2 * la]; v1 += bl3[2 * la + 1]; }
        t3b32[(size_t)node * 10 + la] =
            (unsigned int)f2bf(v0) | ((unsigned int)f2bf(v1) << 16);
    }
}

// ---------------- aggregate 10-dim (bf16 t3) + pooling ----------------
__global__ __launch_bounds__(256) void agg10_pool(
    const unsigned short* __restrict__ t3b, const int* __restrict__ cnt,
    const unsigned short* __restrict__ colbuf, const float* __restrict__ bl3,
    const int* __restrict__ batch,
    float* __restrict__ gsum, float* __restrict__ gcnt, int N) {
    __shared__ float ls[2816];
    for (int i = threadIdx.x; i < 2816; i += 256) ls[i] = 0.f;
    __syncthreads();

    const int lane = threadIdx.x & 63;
    const int wvi = threadIdx.x >> 6;
    const int la = lane & 15;
    const int qb = lane & 48;
    const int node = blockIdx.x * 16 + wvi * 4 + (lane >> 4);
    const bool valid = node < N;
    const int nodec = valid ? node : N - 1;
    const int deg = cnt[nodec];
    const int d = valid ? min(deg, CAP) : 0;
    const unsigned short* cb = colbuf + (size_t)nodec * CAP;

    float acc = 0.f;
    int nb = (d + 15) >> 4;
    for (int b = 0; b < nb; ++b) {
        int slot = b * 16 + la;
        int idx = (slot < d) ? (int)cb[slot] : N;   // N = t3 zero row
        float vv[16];
#pragma unroll
        for (int j = 0; j < 16; ++j) {
            int s = __shfl(idx, qb + j, 64);
            vv[j] = (la < 10) ? bf2f(t3b[(size_t)s * 20 + la]) : 0.f;
        }
#pragma unroll
        for (int j = 0; j < 16; ++j) acc += vv[j];
    }
    if (valid && la < 10) {
        float self = bf2f(t3b[(size_t)node * 20 + 10 + la]);
        float h = (d > 0) ? (acc / (float)deg + self) : (bl3[la] + self);
        int g = batch[node];
        atomicAdd(&ls[g * 10 + la], h);
        if (la == 0) atomicAdd(&ls[2560 + g], 1.0f);
    }
    __syncthreads();
    for (int i = threadIdx.x; i < 2816; i += 256) {
        float v = ls[i];
        if (v != 0.f) {
            if (i < 2560) atomicAdd(&gsum[i], v);
            else          atomicAdd(&gcnt[i - 2560], v);
        }
    }
}

// ---------------- mean + log_softmax ----------------
__global__ void finalize_pool(const float* __restrict__ gsum,
                              const float* __restrict__ gcnt,
                              float* __restrict__ out, int G) {
    int g = blockIdx.x * blockDim.x + threadIdx.x;
    if (g >= G) return;
    float inv = 1.0f / fmaxf(gcnt[g], 1.0f);
    float p[10];
    float m = -1e30f;
#pragma unroll
    for (int c = 0; c < 10; ++c) { p[c] = gsum[g * 10 + c] * inv; m = fmaxf(m, p[c]); }
    float s = 0.f;
#pragma unroll
    for (int c = 0; c < 10; ++c) s += expf(p[c] - m);
    float lse = logf(s);
#pragma unroll
    for (int c = 0; c < 10; ++c) out[g * 10 + c] = p[c] - m - lse;
}

extern "C" void kernel_launch(void* const* d_in, const int* in_sizes, int n_in,
                              void* d_out, int out_size, void* d_ws, size_t ws_size,
                              hipStream_t stream) {
    const float* x    = (const float*)d_in[0];
    const int*   ei   = (const int*)d_in[1];
    const int*   batch= (const int*)d_in[2];
    const float* Wl1  = (const float*)d_in[3];
    const float* bl1  = (const float*)d_in[4];
    const float* Wr1  = (const float*)d_in[5];
    const float* Wl2  = (const float*)d_in[6];
    const float* bl2  = (const float*)d_in[7];
    const float* Wr2  = (const float*)d_in[8];
    const float* Wl3  = (const float*)d_in[9];
    const float* bl3  = (const float*)d_in[10];
    const float* Wr3  = (const float*)d_in[11];
    float* out = (float*)d_out;

    const int N = in_sizes[2];
    const int E = in_sizes[1] / 2;
    const int G = out_size / 10;
    const int ablk = (E + EB - 1) / EB;
    const int nbk  = (N + 127) >> 7;

    char* ws = (char*)d_ws;
    size_t o = 0;
    float* gsum   = (float*)(ws + o); o += (size_t)G * 10 * 4;
    float* gcnt   = (float*)(ws + o); o += (size_t)G * 4;
    size_t zero_bytes = (o + 255) & ~(size_t)255;
    o = zero_bytes;
    int*            cnt    = (int*)(ws + o);            o += (size_t)N * 4;
    unsigned short* colbuf = (unsigned short*)(ws + o); o += ((size_t)N * CAP * 2 + 255) & ~(size_t)255;
    short*          Wq     = (short*)(ws + o);          o += (size_t)10240 * 2;
    float*          cbv    = (float*)(ws + o);          o += 40 * 4;
    o = (o + 255) & ~(size_t)255;
    unsigned short* mm     = (unsigned short*)(ws + o); o += (size_t)(N + 1) * 40 * 2;  // [m1|m1r] bf16 (+zero row)
    o = (o + 255) & ~(size_t)255;
    float*          bmrow  = (float*)(ws + o);          o += (size_t)N * 40 * 4;        // [bm|bmr] fp32
    unsigned short* q2b    = (unsigned short*)(ws + o); o += (size_t)(N + 1) * 20 * 2;  // q2 bf16 (+zero row)
    o = (o + 255) & ~(size_t)255;
    float*          rbuf   = (float*)(ws + o);          o += (size_t)N * 20 * 4;        // rvec fp32
    unsigned short* t3b    = (unsigned short*)(ws + o); o += (size_t)(N + 1) * 20 * 2;  // t3 bf16 (+zero row)
    o = (o + 255) & ~(size_t)255;
    unsigned int*   bedges = (unsigned int*)(ws + o);   o += (size_t)nbk * ablk * CAP * 4;
    int*            runCnt = (int*)(ws + o);            o += (size_t)ablk * nbk * 4;

    int zero_words = (int)(zero_bytes / 4);
    int zblocks = (zero_words + 255) / 256;
    prep_weights<<<ablk + 2 + zblocks, 256, 0, stream>>>(
        Wl1, Wr1, Wl2, Wr2, Wl3, Wr3, bl1, bl2, Wq, cbv,
        (int*)ws, zero_words,
        (unsigned int*)mm, (unsigned int*)q2b, (unsigned int*)t3b, N,
        ei, E, ablk, nbk, bedges, runCnt);

    int gblocks = (N + 63) / 64;
    int ablocks = (N + 15) / 16;
    fillX<<<nbk + gblocks, 256, 0, stream>>>(x, Wq, cbv, mm, bmrow, N,
                                             nbk, ablk, bedges, runCnt,
                                             cnt, colbuf);
    // collapsed layers 1-3 message aggregation (40-dim, L2-resident table)
    aggM<<<ablocks, 256, 0, stream>>>((const uint2*)mm, cnt, colbuf,
                                      bmrow, q2b, rbuf, N);
    // layer-2/3 aggregate over 20-dim q2 -> t3 (bf16)
    agg20<<<ablocks, 256, 0, stream>>>((const unsigned int*)q2b, cnt, colbuf,
                                       (const float2*)rbuf, bl3,
                                       (unsigned int*)t3b, N);
    // layer-3 aggregate + pooling
    agg10_pool<<<ablocks, 256, 0, stream>>>(t3b, cnt, colbuf, bl3, batch,
                                            gsum, gcnt, N);
    finalize_pool<<<1, 256, 0, stream>>>(gsum, gcnt, out, G);
}

// Round 4
// 198.983 us; speedup vs baseline: 1.3461x; 1.3461x over previous
//
#include <hip/hip_runtime.h>

// GraphSAGE: 3x (project -> mean-aggregate) + mean pool + log_softmax.
// R21: fix R20's serial matrix-chain straggler (142us, one block latency-bound
//      on scalar global loads). Chain restructured for register reuse:
//        wtT[128][20] / m2M[128][40] in LDS (lane-broadcast reads),
//        thread owns a k-row, W-row loaded once as float4 and reused across
//        all 20/40 output columns. Same FP summation order -> bit-identical.
//      Pipeline unchanged otherwise:
//      prep (scatter + chain -> Wq,cbv) -> fillX (CSR fill + Nx128x80 MFMA)
//        -> aggM (40-dim gather, L2-resident) -> agg20 -> agg10_pool -> finalize.

#define CAP 48
#define EB 4096

typedef __attribute__((ext_vector_type(8))) short short8;
typedef __attribute__((ext_vector_type(4))) float floatx4;

static __device__ __forceinline__ unsigned short f2bf(float f) {
    unsigned int u = __float_as_uint(f);
    u += 0x7FFFu + ((u >> 16) & 1u);
    return (unsigned short)(u >> 16);
}
static __device__ __forceinline__ float bf2f(unsigned short b) {
    return __uint_as_float(((unsigned int)b) << 16);
}

// ---------------- prep: bucket scatter + combined-matrix chain + zeroing ----
// Combined matrices (one block, LDS-staged with register reuse):
//   wtT[f][c] : c<10 -> Wl3[f][c], c>=10 -> Wr3[f][c-10]          (128x20)
//   m2M[k][cc]: cc<20 -> sum_f Wl2[k][f] wtT[f][cc]               (128x40)
//               cc>=20 -> sum_f Wr2[k][f] wtT[f][cc-20]
//   P[k][f80] : f<40 -> sum_j Wl1[k][j] m2M[j][f]
//               f>=40 -> sum_j Wr1[k][j] m2M[j][f-40]
//   Wq = bf16 MFMA-packed P (5 m-tiles x 4 k-steps x 64 lanes x 8)
//   cbv[0..19]  = bl1 @ m2   ;  cbv[20..39] = bl1 @ m2r + bl2 @ wt
__global__ void prep_weights(const float* __restrict__ Wl1, const float* __restrict__ Wr1,
                             const float* __restrict__ Wl2, const float* __restrict__ Wr2,
                             const float* __restrict__ Wl3, const float* __restrict__ Wr3,
                             const float* __restrict__ bl1, const float* __restrict__ bl2,
                             short* __restrict__ Wq, float* __restrict__ cbv,
                             int* __restrict__ zero_base, int zero_words,
                             unsigned int* __restrict__ mmz, unsigned int* __restrict__ q2b32,
                             unsigned int* __restrict__ t3b32, int N,
                             const int* __restrict__ ei, int E, int ablk, int nbk,
                             unsigned int* __restrict__ bedges, int* __restrict__ runCnt) {
    __shared__ int hist[512];
    __shared__ float wtT_s[128 * 20];
    __shared__ float m2M_s[128 * 40];
    if (blockIdx.x < (unsigned)ablk) {
        for (int i = threadIdx.x; i < nbk; i += 256) hist[i] = 0;
        __syncthreads();
        int e0 = blockIdx.x * EB + threadIdx.x;
        unsigned int pk[16];
        int bk[16], loc[16];
#pragma unroll
        for (int k = 0; k < 16; ++k) {
            int e = e0 + k * 256;
            if (e < E) {
                int src = ei[e];
                int dst = ei[E + e];
                bk[k] = dst >> 7;
                pk[k] = ((unsigned int)(dst & 127) << 16) | (unsigned int)src;
                loc[k] = atomicAdd(&hist[bk[k]], 1);    // LDS atomic
            } else bk[k] = -1;
        }
        __syncthreads();
        for (int i = threadIdx.x; i < nbk; i += 256)
            runCnt[(size_t)blockIdx.x * nbk + i] = hist[i];
#pragma unroll
        for (int k = 0; k < 16; ++k)
            if (bk[k] >= 0 && loc[k] < CAP)
                bedges[((size_t)bk[k] * ablk + blockIdx.x) * CAP + loc[k]] = pk[k];
        return;
    }
    int rb = blockIdx.x - ablk;
    if (rb == 0) {
        const int tid = threadIdx.x;
        // stage 1: wtT[f][c] (natural layout of Wl3/Wr3)
        for (int i = tid; i < 2560; i += 256) {
            int f = i / 20, c = i - f * 20;
            wtT_s[i] = (c < 10) ? Wl3[f * 10 + c] : Wr3[f * 10 + (c - 10)];
        }
        __syncthreads();
        // stage 2: m2M[k][half*20+c], thread owns (k, half); W2-row in regs
        {
            int k = tid & 127, half = tid >> 7;
            const float* w2row = (half ? Wr2 : Wl2) + (size_t)k * 128;
            float acc[20];
#pragma unroll
            for (int c = 0; c < 20; ++c) acc[c] = 0.f;
            for (int f4 = 0; f4 < 32; ++f4) {
                float4 wv = *(const float4*)&w2row[f4 * 4];
#pragma unroll
                for (int e = 0; e < 4; ++e) {
                    float w = (e == 0) ? wv.x : (e == 1) ? wv.y : (e == 2) ? wv.z : wv.w;
                    const float* wt = &wtT_s[(f4 * 4 + e) * 20];
#pragma unroll
                    for (int c = 0; c < 20; ++c) acc[c] += w * wt[c];
                }
            }
            float* dst = &m2M_s[k * 40 + half * 20];
#pragma unroll
            for (int c = 0; c < 20; ++c) dst[c] = acc[c];
        }
        __syncthreads();
        // stage 3: P[k][f], thread owns (k, srcHalf); W1-row in regs
        {
            int k = tid & 127, sh = tid >> 7;
            const float* wrow = (sh ? Wr1 : Wl1) + (size_t)k * 128;
            float acc[40];
#pragma unroll
            for (int c = 0; c < 40; ++c) acc[c] = 0.f;
            for (int j4 = 0; j4 < 32; ++j4) {
                float4 wv = *(const float4*)&wrow[j4 * 4];
#pragma unroll
                for (int e = 0; e < 4; ++e) {
                    float w = (e == 0) ? wv.x : (e == 1) ? wv.y : (e == 2) ? wv.z : wv.w;
                    const float* mr = &m2M_s[(j4 * 4 + e) * 40];
#pragma unroll
                    for (int c = 0; c < 40; ++c) acc[c] += w * mr[c];
                }
            }
            int ks = k >> 5, rem = k & 31, q = rem >> 3, jj = rem & 7;
#pragma unroll
            for (int c = 0; c < 40; ++c) {
                int f = sh * 40 + c;
                int mi = f >> 4, m = f & 15;
                int l = q * 16 + m;
                Wq[(((mi * 4 + ks) * 64) + l) * 8 + jj] = (short)f2bf(acc[c]);
            }
        }
        // stage 4: cbv (reads LDS written before the last sync)
        if (tid < 40) {
            float s = 0.f;
            if (tid < 20) {
                for (int k = 0; k < 128; ++k) s += bl1[k] * m2M_s[k * 40 + tid];
            } else {
                int c = tid - 20;
                for (int k = 0; k < 128; ++k) s += bl1[k] * m2M_s[k * 40 + 20 + c];
                for (int f = 0; f < 128; ++f) s += bl2[f] * wtT_s[f * 20 + c];
            }
            cbv[tid] = s;
        }
        return;
    }
    if (rb == 1) {
        // zero rows: mm (20 uints), q2b (10), t3b (10)
        if (threadIdx.x < 20) mmz[(size_t)N * 20 + threadIdx.x] = 0;
        if (threadIdx.x >= 32 && threadIdx.x < 42)
            q2b32[(size_t)N * 10 + (threadIdx.x - 32)] = 0;
        if (threadIdx.x >= 64 && threadIdx.x < 74)
            t3b32[(size_t)N * 10 + (threadIdx.x - 64)] = 0;
        return;
    }
    int i = (rb - 2) * 256 + threadIdx.x;
    if (i < zero_words) zero_base[i] = 0;
}

// ---------------- fillX: phase-B CSR fill + dense x @ [A|C|B|D] ----------------
// Projection blocks: 64 nodes/block, wave w owns nodes node0+w*16+m, computes
// all 80 outputs (5 m-tiles). f<40 -> mm row [m1(20)|m1r(20)] bf16 (80B);
// f>=40 -> bmrow row [bm(20)|bmr(20)] fp32 (+cbv consts).
__global__ __launch_bounds__(256) void fillX(
    const float* __restrict__ x, const short* __restrict__ Wq,
    const float* __restrict__ cbv, unsigned short* __restrict__ mm,
    float* __restrict__ bmrow, int N, int nbk, int ablk,
    const unsigned int* __restrict__ bedges, const int* __restrict__ runCnt,
    int* __restrict__ cnt, unsigned short* __restrict__ colbuf) {
    __shared__ unsigned short As[64 * 136];
    __shared__ int lcnt[128];
    if (blockIdx.x >= (unsigned)nbk) {
        int blk = blockIdx.x - nbk;
        int node0 = blk * 64;
#pragma unroll
        for (int c = 0; c < 8; ++c) {
            int idx = c * 256 + threadIdx.x;
            int r = idx >> 5;
            int c4 = idx & 31;
            int row = node0 + r;
            float4 v = make_float4(0.f, 0.f, 0.f, 0.f);
            if (row < N) v = *(const float4*)&x[(size_t)row * 128 + c4 * 4];
            ushort4 p;
            p.x = f2bf(v.x); p.y = f2bf(v.y); p.z = f2bf(v.z); p.w = f2bf(v.w);
            *(ushort4*)&As[r * 136 + c4 * 4] = p;
        }
        __syncthreads();

        const int w = threadIdx.x >> 6;
        const int lane = threadIdx.x & 63;
        const int q = lane >> 4;
        const int m = lane & 15;

        floatx4 acc[5] = {};
#pragma unroll
        for (int s = 0; s < 4; ++s) {
            short8 bfrag = *(const short8*)&As[(w * 16 + m) * 136 + s * 32 + q * 8];
#pragma unroll
            for (int mi = 0; mi < 5; ++mi) {
                short8 wf = *(const short8*)&Wq[((mi * 4 + s) * 64 + lane) * 8];
                acc[mi] = __builtin_amdgcn_mfma_f32_16x16x32_bf16(
                    wf, bfrag, acc[mi], 0, 0, 0);
            }
        }
        int node = node0 + w * 16 + m;
        if (node < N) {
#pragma unroll
            for (int mi = 0; mi < 5; ++mi) {
                int f0 = mi * 16 + q * 4;
                floatx4 a = acc[mi];
                if (f0 < 40) {
                    ushort4 p;
                    p.x = f2bf(a[0]); p.y = f2bf(a[1]);
                    p.z = f2bf(a[2]); p.w = f2bf(a[3]);
                    *(ushort4*)&mm[(size_t)node * 40 + f0] = p;
                } else {
                    float4 cb = *(const float4*)&cbv[f0 - 40];
                    float4 o = make_float4(a[0] + cb.x, a[1] + cb.y,
                                           a[2] + cb.z, a[3] + cb.w);
                    *(float4*)&bmrow[(size_t)node * 40 + (f0 - 40)] = o;
                }
            }
        }
    } else {
        int b = blockIdx.x;
        if (threadIdx.x < 128) lcnt[threadIdx.x] = 0;
        __syncthreads();
        for (int blk = threadIdx.x; blk < ablk; blk += 256) {
            int c = runCnt[(size_t)blk * nbk + b];
            c = min(c, CAP);
            size_t ebase = ((size_t)b * ablk + blk) * CAP;
            for (int i = 0; i < c; ++i) {
                unsigned int pk = bedges[ebase + i];
                int dl = pk >> 16;
                int slot = atomicAdd(&lcnt[dl], 1);    // LDS atomic
                if (slot < CAP)
                    colbuf[(size_t)(b * 128 + dl) * CAP + slot] =
                        (unsigned short)(pk & 0xFFFFu);
            }
        }
        __syncthreads();
        int node = b * 128 + threadIdx.x;
        if (threadIdx.x < 128 && node < N) cnt[node] = lcnt[threadIdx.x];
    }
}

// ---------------- aggM: 40-dim gather over mm (80B rows, L2-resident) --------
// q2[n] = mean_s m1[s] + bm[n]  (bf16 out);  rvec[n] = mean_s m1r[s] + bmr[n].
__global__ __launch_bounds__(256) void aggM(
    const uint2* __restrict__ mm2, const int* __restrict__ cnt,
    const unsigned short* __restrict__ colbuf, const float* __restrict__ bmrow,
    unsigned short* __restrict__ q2b, float* __restrict__ rbuf, int N) {
    const int lane = threadIdx.x & 63;
    const int wvi = threadIdx.x >> 6;
    const int la = lane & 15;
    const int qb = lane & 48;
    const int node = blockIdx.x * 16 + wvi * 4 + (lane >> 4);
    const bool valid = node < N;
    const int nodec = valid ? node : N - 1;
    const int deg = cnt[nodec];
    const int d = valid ? min(deg, CAP) : 0;
    const unsigned short* cb = colbuf + (size_t)nodec * CAP;

    float f0 = 0.f, f1 = 0.f, f2 = 0.f, f3 = 0.f;
    int nb = (d + 15) >> 4;
    for (int b = 0; b < nb; ++b) {
        int slot = b * 16 + la;
        int idx = (slot < d) ? (int)cb[slot] : N;   // N = mm zero row
        uint2 vv[16];
#pragma unroll
        for (int j = 0; j < 16; ++j) {
            int s = __shfl(idx, qb + j, 64);
            uint2 z; z.x = 0u; z.y = 0u;
            vv[j] = (la < 10) ? mm2[(size_t)s * 10 + la] : z;
        }
#pragma unroll
        for (int j = 0; j < 16; ++j) {
            f0 += bf2f((unsigned short)(vv[j].x & 0xFFFF));
            f1 += bf2f((unsigned short)(vv[j].x >> 16));
            f2 += bf2f((unsigned short)(vv[j].y & 0xFFFF));
            f3 += bf2f((unsigned short)(vv[j].y >> 16));
        }
    }
    if (valid && la < 10) {
        float inv = 1.0f / (float)max(deg, 1);
        float4 bv = *(const float4*)&bmrow[(size_t)node * 40 + la * 4];
        float o0 = f0 * inv + bv.x, o1 = f1 * inv + bv.y;
        float o2 = f2 * inv + bv.z, o3 = f3 * inv + bv.w;
        if (la < 5) {
            ushort4 p;
            p.x = f2bf(o0); p.y = f2bf(o1); p.z = f2bf(o2); p.w = f2bf(o3);
            *(ushort4*)&q2b[(size_t)node * 20 + la * 4] = p;
        } else {
            *(float4*)&rbuf[(size_t)node * 20 + (la - 5) * 4] =
                make_float4(o0, o1, o2, o3);
        }
    }
}

// ---------------- layer-2 aggregate (20-dim q2) + t3 assembly ----------------
// t3[n] cols 0..9 = mean_s q2_l[s] + r_l[n] + bl3 (biased trick),
//       cols 10..19 = mean_s q2_r[s] + r_r[n].  Stored bf16 (40B rows).
__global__ __launch_bounds__(256) void agg20(
    const unsigned int* __restrict__ q2b32, const int* __restrict__ cnt,
    const unsigned short* __restrict__ colbuf, const float2* __restrict__ rbuf2,
    const float* __restrict__ bl3, unsigned int* __restrict__ t3b32, int N) {
    const int lane = threadIdx.x & 63;
    const int wvi = threadIdx.x >> 6;
    const int la = lane & 15;
    const int qb = lane & 48;
    const int node = blockIdx.x * 16 + wvi * 4 + (lane >> 4);
    const bool valid = node < N;
    const int nodec = valid ? node : N - 1;
    const int deg = cnt[nodec];
    const int d = valid ? min(deg, CAP) : 0;
    const unsigned short* cb = colbuf + (size_t)nodec * CAP;

    float f0 = 0.f, f1 = 0.f;
    int nb = (d + 15) >> 4;
    for (int b = 0; b < nb; ++b) {
        int slot = b * 16 + la;
        int idx = (slot < d) ? (int)cb[slot] : N;   // N = q2 zero row
        unsigned int vv[16];
#pragma unroll
        for (int j = 0; j < 16; ++j) {
            int s = __shfl(idx, qb + j, 64);
            vv[j] = (la < 10) ? q2b32[(size_t)s * 10 + la] : 0u;
        }
#pragma unroll
        for (int j = 0; j < 16; ++j) {
            f0 += bf2f((unsigned short)(vv[j] & 0xFFFF));
            f1 += bf2f((unsigned short)(vv[j] >> 16));
        }
    }
    if (valid && la < 10) {
        float inv = 1.0f / (float)max(deg, 1);
        float2 rv = rbuf2[(size_t)node * 10 + la];
        float v0 = f0 * inv + rv.x;
        float v1 = f1 * inv + rv.y;
        if (la < 5) { v0 += bl3[2 * la]; v1 += bl3[2 * la + 1]; }
        t3b32[(size_t)node * 10 + la] =
            (unsigned int)f2bf(v0) | ((unsigned int)f2bf(v1) << 16);
    }
}

// ---------------- aggregate 10-dim (bf16 t3) + pooling ----------------
__global__ __launch_bounds__(256) void agg10_pool(
    const unsigned short* __restrict__ t3b, const int* __restrict__ cnt,
    const unsigned short* __restrict__ colbuf, const float* __restrict__ bl3,
    const int* __restrict__ batch,
    float* __restrict__ gsum, float* __restrict__ gcnt, int N) {
    __shared__ float ls[2816];
    for (int i = threadIdx.x; i < 2816; i += 256) ls[i] = 0.f;
    __syncthreads();

    const int lane = threadIdx.x & 63;
    const int wvi = threadIdx.x >> 6;
    const int la = lane & 15;
    const int qb = lane & 48;
    const int node = blockIdx.x * 16 + wvi * 4 + (lane >> 4);
    const bool valid = node < N;
    const int nodec = valid ? node : N - 1;
    const int deg = cnt[nodec];
    const int d = valid ? min(deg, CAP) : 0;
    const unsigned short* cb = colbuf + (size_t)nodec * CAP;

    float acc = 0.f;
    int nb = (d + 15) >> 4;
    for (int b = 0; b < nb; ++b) {
        int slot = b * 16 + la;
        int idx = (slot < d) ? (int)cb[slot] : N;   // N = t3 zero row
        float vv[16];
#pragma unroll
        for (int j = 0; j < 16; ++j) {
            int s = __shfl(idx, qb + j, 64);
            vv[j] = (la < 10) ? bf2f(t3b[(size_t)s * 20 + la]) : 0.f;
        }
#pragma unroll
        for (int j = 0; j < 16; ++j) acc += vv[j];
    }
    if (valid && la < 10) {
        float self = bf2f(t3b[(size_t)node * 20 + 10 + la]);
        float h = (d > 0) ? (acc / (float)deg + self) : (bl3[la] + self);
        int g = batch[node];
        atomicAdd(&ls[g * 10 + la], h);
        if (la == 0) atomicAdd(&ls[2560 + g], 1.0f);
    }
    __syncthreads();
    for (int i = threadIdx.x; i < 2816; i += 256) {
        float v = ls[i];
        if (v != 0.f) {
            if (i < 2560) atomicAdd(&gsum[i], v);
            else          atomicAdd(&gcnt[i - 2560], v);
        }
    }
}

// ---------------- mean + log_softmax ----------------
__global__ void finalize_pool(const float* __restrict__ gsum,
                              const float* __restrict__ gcnt,
                              float* __restrict__ out, int G) {
    int g = blockIdx.x * blockDim.x + threadIdx.x;
    if (g >= G) return;
    float inv = 1.0f / fmaxf(gcnt[g], 1.0f);
    float p[10];
    float m = -1e30f;
#pragma unroll
    for (int c = 0; c < 10; ++c) { p[c] = gsum[g * 10 + c] * inv; m = fmaxf(m, p[c]); }
    float s = 0.f;
#pragma unroll
    for (int c = 0; c < 10; ++c) s += expf(p[c] - m);
    float lse = logf(s);
#pragma unroll
    for (int c = 0; c < 10; ++c) out[g * 10 + c] = p[c] - m - lse;
}

extern "C" void kernel_launch(void* const* d_in, const int* in_sizes, int n_in,
                              void* d_out, int out_size, void* d_ws, size_t ws_size,
                              hipStream_t stream) {
    const float* x    = (const float*)d_in[0];
    const int*   ei   = (const int*)d_in[1];
    const int*   batch= (const int*)d_in[2];
    const float* Wl1  = (const float*)d_in[3];
    const float* bl1  = (const float*)d_in[4];
    const float* Wr1  = (const float*)d_in[5];
    const float* Wl2  = (const float*)d_in[6];
    const float* bl2  = (const float*)d_in[7];
    const float* Wr2  = (const float*)d_in[8];
    const float* Wl3  = (const float*)d_in[9];
    const float* bl3  = (const float*)d_in[10];
    const float* Wr3  = (const float*)d_in[11];
    float* out = (float*)d_out;

    const int N = in_sizes[2];
    const int E = in_sizes[1] / 2;
    const int G = out_size / 10;
    const int ablk = (E + EB - 1) / EB;
    const int nbk  = (N + 127) >> 7;

    char* ws = (char*)d_ws;
    size_t o = 0;
    float* gsum   = (float*)(ws + o); o += (size_t)G * 10 * 4;
    float* gcnt   = (float*)(ws + o); o += (size_t)G * 4;
    size_t zero_bytes = (o + 255) & ~(size_t)255;
    o = zero_bytes;
    int*            cnt    = (int*)(ws + o);            o += (size_t)N * 4;
    unsigned short* colbuf = (unsigned short*)(ws + o); o += ((size_t)N * CAP * 2 + 255) & ~(size_t)255;
    short*          Wq     = (short*)(ws + o);          o += (size_t)10240 * 2;
    float*          cbv    = (float*)(ws + o);          o += 40 * 4;
    o = (o + 255) & ~(size_t)255;
    unsigned short* mm     = (unsigned short*)(ws + o); o += (size_t)(N + 1) * 40 * 2;  // [m1|m1r] bf16 (+zero row)
    o = (o + 255) & ~(size_t)255;
    float*          bmrow  = (float*)(ws + o);          o += (size_t)N * 40 * 4;        // [bm|bmr] fp32
    unsigned short* q2b    = (unsigned short*)(ws + o); o += (size_t)(N + 1) * 20 * 2;  // q2 bf16 (+zero row)
    o = (o + 255) & ~(size_t)255;
    float*          rbuf   = (float*)(ws + o);          o += (size_t)N * 20 * 4;        // rvec fp32
    unsigned short* t3b    = (unsigned short*)(ws + o); o += (size_t)(N + 1) * 20 * 2;  // t3 bf16 (+zero row)
    o = (o + 255) & ~(size_t)255;
    unsigned int*   bedges = (unsigned int*)(ws + o);   o += (size_t)nbk * ablk * CAP * 4;
    int*            runCnt = (int*)(ws + o);            o += (size_t)ablk * nbk * 4;

    int zero_words = (int)(zero_bytes / 4);
    int zblocks = (zero_words + 255) / 256;
    prep_weights<<<ablk + 2 + zblocks, 256, 0, stream>>>(
        Wl1, Wr1, Wl2, Wr2, Wl3, Wr3, bl1, bl2, Wq, cbv,
        (int*)ws, zero_words,
        (unsigned int*)mm, (unsigned int*)q2b, (unsigned int*)t3b, N,
        ei, E, ablk, nbk, bedges, runCnt);

    int gblocks = (N + 63) / 64;
    int ablocks = (N + 15) / 16;
    fillX<<<nbk + gblocks, 256, 0, stream>>>(x, Wq, cbv, mm, bmrow, N,
                                             nbk, ablk, bedges, runCnt,
                                             cnt, colbuf);
    // collapsed layers 1-3 message aggregation (40-dim, L2-resident table)
    aggM<<<ablocks, 256, 0, stream>>>((const uint2*)mm, cnt, colbuf,
                                      bmrow, q2b, rbuf, N);
    // layer-2/3 aggregate over 20-dim q2 -> t3 (bf16)
    agg20<<<ablocks, 256, 0, stream>>>((const unsigned int*)q2b, cnt, colbuf,
                                       (const float2*)rbuf, bl3,
                                       (unsigned int*)t3b, N);
    // layer-3 aggregate + pooling
    agg10_pool<<<ablocks, 256, 0, stream>>>(t3b, cnt, colbuf, bl3, batch,
                                            gsum, gcnt, N);
    finalize_pool<<<1, 256, 0, stream>>>(gsum, gcnt, out, G);
}

// Round 5
// 190.768 us; speedup vs baseline: 1.4040x; 1.0431x over previous
//
#include <hip/hip_runtime.h>

// GraphSAGE: 3x (project -> mean-aggregate) + mean pool + log_softmax.
// R22: parallelize the weight-chain straggler (45.5us, one block on one CU).
//      Split at the m2M -> P dependency edge:
//        prep:  scatter + 4 chain blocks (wtT in LDS, 32 m2M rows each,
//               8 thr/row) -> m2Mg global (20KB) + zero rows/base.
//        prep2: 8 blocks stage3 (P = W1 @ m2M, m2M staged in LDS) -> Wq pack,
//               + 1 block cbv.  Same FP summation order -> bit-identical.
//      Pipeline: prep -> prep2 -> fillX (CSR fill + Nx128x80 MFMA)
//        -> aggM (40-dim gather, L2-resident) -> agg20 -> agg10_pool -> finalize.
//      7 dispatches.

#define CAP 48
#define EB 4096

typedef __attribute__((ext_vector_type(8))) short short8;
typedef __attribute__((ext_vector_type(4))) float floatx4;

static __device__ __forceinline__ unsigned short f2bf(float f) {
    unsigned int u = __float_as_uint(f);
    u += 0x7FFFu + ((u >> 16) & 1u);
    return (unsigned short)(u >> 16);
}
static __device__ __forceinline__ float bf2f(unsigned short b) {
    return __uint_as_float(((unsigned int)b) << 16);
}

// ---------------- prep: bucket scatter + chain stage1/2 + zeroing ----
// Chain (4 blocks, rb<4): wtT[f][c] (128x20, LDS; c<10 -> Wl3[f][c] else
// Wr3[f][c-10]); block rb computes m2M rows j in [rb*32, rb*32+32):
//   m2Mg[j][cc] = sum_f W2half[j][f] * wtT[f][c20],  cc = half*20 + c20
// Thread = (j_local 0..31, cg 0..7), 5 columns each, W2 row via float4.
__global__ void prep_weights(const float* __restrict__ Wl2, const float* __restrict__ Wr2,
                             const float* __restrict__ Wl3, const float* __restrict__ Wr3,
                             float* __restrict__ m2Mg,
                             int* __restrict__ zero_base, int zero_words,
                             unsigned int* __restrict__ mmz, unsigned int* __restrict__ q2b32,
                             unsigned int* __restrict__ t3b32, int N,
                             const int* __restrict__ ei, int E, int ablk, int nbk,
                             unsigned int* __restrict__ bedges, int* __restrict__ runCnt) {
    __shared__ int hist[512];
    __shared__ float wtT_s[128 * 20];
    if (blockIdx.x < (unsigned)ablk) {
        for (int i = threadIdx.x; i < nbk; i += 256) hist[i] = 0;
        __syncthreads();
        int e0 = blockIdx.x * EB + threadIdx.x;
        unsigned int pk[16];
        int bk[16], loc[16];
#pragma unroll
        for (int k = 0; k < 16; ++k) {
            int e = e0 + k * 256;
            if (e < E) {
                int src = ei[e];
                int dst = ei[E + e];
                bk[k] = dst >> 7;
                pk[k] = ((unsigned int)(dst & 127) << 16) | (unsigned int)src;
                loc[k] = atomicAdd(&hist[bk[k]], 1);    // LDS atomic
            } else bk[k] = -1;
        }
        __syncthreads();
        for (int i = threadIdx.x; i < nbk; i += 256)
            runCnt[(size_t)blockIdx.x * nbk + i] = hist[i];
#pragma unroll
        for (int k = 0; k < 16; ++k)
            if (bk[k] >= 0 && loc[k] < CAP)
                bedges[((size_t)bk[k] * ablk + blockIdx.x) * CAP + loc[k]] = pk[k];
        return;
    }
    int rb = blockIdx.x - ablk;
    if (rb < 4) {
        const int tid = threadIdx.x;
        // stage 1: wtT[f][c] (natural layout of Wl3/Wr3)
        for (int i = tid; i < 2560; i += 256) {
            int f = i / 20, c = i - f * 20;
            wtT_s[i] = (c < 10) ? Wl3[f * 10 + c] : Wr3[f * 10 + (c - 10)];
        }
        __syncthreads();
        // stage 2: 32 m2M rows for this block, 8 threads per row (5 cols each)
        int jl = tid >> 3;             // 0..31
        int cg = tid & 7;              // 0..7
        int j = rb * 32 + jl;
        const float* w2row = ((cg < 4) ? Wl2 : Wr2) + (size_t)j * 128;
        int c20 = (cg & 3) * 5;        // column base within wtT's 20
        float acc[5] = {0.f, 0.f, 0.f, 0.f, 0.f};
        for (int f4 = 0; f4 < 32; ++f4) {
            float4 wv = *(const float4*)&w2row[f4 * 4];
#pragma unroll
            for (int e = 0; e < 4; ++e) {
                float w = (e == 0) ? wv.x : (e == 1) ? wv.y : (e == 2) ? wv.z : wv.w;
                const float* wt = &wtT_s[(f4 * 4 + e) * 20 + c20];
#pragma unroll
                for (int i = 0; i < 5; ++i) acc[i] += w * wt[i];
            }
        }
        int cc = (cg >> 2) * 20 + c20;
#pragma unroll
        for (int i = 0; i < 5; ++i) m2Mg[j * 40 + cc + i] = acc[i];
        return;
    }
    if (rb == 4) {
        // zero rows: mm (20 uints), q2b (10), t3b (10)
        if (threadIdx.x < 20) mmz[(size_t)N * 20 + threadIdx.x] = 0;
        if (threadIdx.x >= 32 && threadIdx.x < 42)
            q2b32[(size_t)N * 10 + (threadIdx.x - 32)] = 0;
        if (threadIdx.x >= 64 && threadIdx.x < 74)
            t3b32[(size_t)N * 10 + (threadIdx.x - 64)] = 0;
        return;
    }
    int i = (rb - 5) * 256 + threadIdx.x;
    if (i < zero_words) zero_base[i] = 0;
}

// ---------------- prep2: chain stage3 (P = W1 @ m2M) + Wq pack + cbv ----------
// Blocks 0..7: rows r = b*32 + (tid>>3), r = sh*128 + k; thread computes 5 of
// the 40 columns (cg = tid&7). m2M staged to LDS. Wq packed bf16 MFMA layout.
// Block 8: cbv[0..19] = bl1 @ m2 ; cbv[20..39] = bl1 @ m2r + bl2 @ wt.
__global__ __launch_bounds__(256) void prep2(
    const float* __restrict__ Wl1, const float* __restrict__ Wr1,
    const float* __restrict__ Wl3, const float* __restrict__ Wr3,
    const float* __restrict__ bl1, const float* __restrict__ bl2,
    const float* __restrict__ m2Mg, short* __restrict__ Wq,
    float* __restrict__ cbv) {
    __shared__ float m2s[128 * 40];
    const int tid = threadIdx.x;
    if (blockIdx.x == 8) {
        if (tid < 40) {
            float s = 0.f;
            if (tid < 20) {
                for (int k = 0; k < 128; ++k) s += bl1[k] * m2Mg[k * 40 + tid];
            } else {
                int c = tid - 20;
                for (int k = 0; k < 128; ++k) s += bl1[k] * m2Mg[k * 40 + 20 + c];
                for (int f = 0; f < 128; ++f) {
                    float wt = (c < 10) ? Wl3[f * 10 + c] : Wr3[f * 10 + (c - 10)];
                    s += bl2[f] * wt;
                }
            }
            cbv[tid] = s;
        }
        return;
    }
    for (int i = tid; i < 5120; i += 256) m2s[i] = m2Mg[i];
    __syncthreads();
    int rl = tid >> 3;                 // 0..31
    int cg = tid & 7;                  // 0..7
    int r = blockIdx.x * 32 + rl;      // 0..255
    int sh = r >> 7, k = r & 127;
    const float* wrow = (sh ? Wr1 : Wl1) + (size_t)k * 128;
    int c0 = cg * 5;
    float acc[5] = {0.f, 0.f, 0.f, 0.f, 0.f};
    for (int j4 = 0; j4 < 32; ++j4) {
        float4 wv = *(const float4*)&wrow[j4 * 4];
#pragma unroll
        for (int e = 0; e < 4; ++e) {
            float w = (e == 0) ? wv.x : (e == 1) ? wv.y : (e == 2) ? wv.z : wv.w;
            const float* mr = &m2s[(j4 * 4 + e) * 40 + c0];
#pragma unroll
            for (int i = 0; i < 5; ++i) acc[i] += w * mr[i];
        }
    }
    int ks = k >> 5, rem = k & 31, q = rem >> 3, jj = rem & 7;
#pragma unroll
    for (int i = 0; i < 5; ++i) {
        int f = sh * 40 + c0 + i;
        int mi = f >> 4, m = f & 15;
        int l = q * 16 + m;
        Wq[(((mi * 4 + ks) * 64) + l) * 8 + jj] = (short)f2bf(acc[i]);
    }
}

// ---------------- fillX: phase-B CSR fill + dense x @ [A|C|B|D] ----------------
// Projection blocks: 64 nodes/block, wave w owns nodes node0+w*16+m, computes
// all 80 outputs (5 m-tiles). f<40 -> mm row [m1(20)|m1r(20)] bf16 (80B);
// f>=40 -> bmrow row [bm(20)|bmr(20)] fp32 (+cbv consts).
__global__ __launch_bounds__(256) void fillX(
    const float* __restrict__ x, const short* __restrict__ Wq,
    const float* __restrict__ cbv, unsigned short* __restrict__ mm,
    float* __restrict__ bmrow, int N, int nbk, int ablk,
    const unsigned int* __restrict__ bedges, const int* __restrict__ runCnt,
    int* __restrict__ cnt, unsigned short* __restrict__ colbuf) {
    __shared__ unsigned short As[64 * 136];
    __shared__ int lcnt[128];
    if (blockIdx.x >= (unsigned)nbk) {
        int blk = blockIdx.x - nbk;
        int node0 = blk * 64;
#pragma unroll
        for (int c = 0; c < 8; ++c) {
            int idx = c * 256 + threadIdx.x;
            int r = idx >> 5;
            int c4 = idx & 31;
            int row = node0 + r;
            float4 v = make_float4(0.f, 0.f, 0.f, 0.f);
            if (row < N) v = *(const float4*)&x[(size_t)row * 128 + c4 * 4];
            ushort4 p;
            p.x = f2bf(v.x); p.y = f2bf(v.y); p.z = f2bf(v.z); p.w = f2bf(v.w);
            *(ushort4*)&As[r * 136 + c4 * 4] = p;
        }
        __syncthreads();

        const int w = threadIdx.x >> 6;
        const int lane = threadIdx.x & 63;
        const int q = lane >> 4;
        const int m = lane & 15;

        floatx4 acc[5] = {};
#pragma unroll
        for (int s = 0; s < 4; ++s) {
            short8 bfrag = *(const short8*)&As[(w * 16 + m) * 136 + s * 32 + q * 8];
#pragma unroll
            for (int mi = 0; mi < 5; ++mi) {
                short8 wf = *(const short8*)&Wq[((mi * 4 + s) * 64 + lane) * 8];
                acc[mi] = __builtin_amdgcn_mfma_f32_16x16x32_bf16(
                    wf, bfrag, acc[mi], 0, 0, 0);
            }
        }
        int node = node0 + w * 16 + m;
        if (node < N) {
#pragma unroll
            for (int mi = 0; mi < 5; ++mi) {
                int f0 = mi * 16 + q * 4;
                floatx4 a = acc[mi];
                if (f0 < 40) {
                    ushort4 p;
                    p.x = f2bf(a[0]); p.y = f2bf(a[1]);
                    p.z = f2bf(a[2]); p.w = f2bf(a[3]);
                    *(ushort4*)&mm[(size_t)node * 40 + f0] = p;
                } else {
                    float4 cb = *(const float4*)&cbv[f0 - 40];
                    float4 o = make_float4(a[0] + cb.x, a[1] + cb.y,
                                           a[2] + cb.z, a[3] + cb.w);
                    *(float4*)&bmrow[(size_t)node * 40 + (f0 - 40)] = o;
                }
            }
        }
    } else {
        int b = blockIdx.x;
        if (threadIdx.x < 128) lcnt[threadIdx.x] = 0;
        __syncthreads();
        for (int blk = threadIdx.x; blk < ablk; blk += 256) {
            int c = runCnt[(size_t)blk * nbk + b];
            c = min(c, CAP);
            size_t ebase = ((size_t)b * ablk + blk) * CAP;
            for (int i = 0; i < c; ++i) {
                unsigned int pk = bedges[ebase + i];
                int dl = pk >> 16;
                int slot = atomicAdd(&lcnt[dl], 1);    // LDS atomic
                if (slot < CAP)
                    colbuf[(size_t)(b * 128 + dl) * CAP + slot] =
                        (unsigned short)(pk & 0xFFFFu);
            }
        }
        __syncthreads();
        int node = b * 128 + threadIdx.x;
        if (threadIdx.x < 128 && node < N) cnt[node] = lcnt[threadIdx.x];
    }
}

// ---------------- aggM: 40-dim gather over mm (80B rows, L2-resident) --------
// q2[n] = mean_s m1[s] + bm[n]  (bf16 out);  rvec[n] = mean_s m1r[s] + bmr[n].
__global__ __launch_bounds__(256) void aggM(
    const uint2* __restrict__ mm2, const int* __restrict__ cnt,
    const unsigned short* __restrict__ colbuf, const float* __restrict__ bmrow,
    unsigned short* __restrict__ q2b, float* __restrict__ rbuf, int N) {
    const int lane = threadIdx.x & 63;
    const int wvi = threadIdx.x >> 6;
    const int la = lane & 15;
    const int qb = lane & 48;
    const int node = blockIdx.x * 16 + wvi * 4 + (lane >> 4);
    const bool valid = node < N;
    const int nodec = valid ? node : N - 1;
    const int deg = cnt[nodec];
    const int d = valid ? min(deg, CAP) : 0;
    const unsigned short* cb = colbuf + (size_t)nodec * CAP;

    float f0 = 0.f, f1 = 0.f, f2 = 0.f, f3 = 0.f;
    int nb = (d + 15) >> 4;
    for (int b = 0; b < nb; ++b) {
        int slot = b * 16 + la;
        int idx = (slot < d) ? (int)cb[slot] : N;   // N = mm zero row
        uint2 vv[16];
#pragma unroll
        for (int j = 0; j < 16; ++j) {
            int s = __shfl(idx, qb + j, 64);
            uint2 z; z.x = 0u; z.y = 0u;
            vv[j] = (la < 10) ? mm2[(size_t)s * 10 + la] : z;
        }
#pragma unroll
        for (int j = 0; j < 16; ++j) {
            f0 += bf2f((unsigned short)(vv[j].x & 0xFFFF));
            f1 += bf2f((unsigned short)(vv[j].x >> 16));
            f2 += bf2f((unsigned short)(vv[j].y & 0xFFFF));
            f3 += bf2f((unsigned short)(vv[j].y >> 16));
        }
    }
    if (valid && la < 10) {
        float inv = 1.0f / (float)max(deg, 1);
        float4 bv = *(const float4*)&bmrow[(size_t)node * 40 + la * 4];
        float o0 = f0 * inv + bv.x, o1 = f1 * inv + bv.y;
        float o2 = f2 * inv + bv.z, o3 = f3 * inv + bv.w;
        if (la < 5) {
            ushort4 p;
            p.x = f2bf(o0); p.y = f2bf(o1); p.z = f2bf(o2); p.w = f2bf(o3);
            *(ushort4*)&q2b[(size_t)node * 20 + la * 4] = p;
        } else {
            *(float4*)&rbuf[(size_t)node * 20 + (la - 5) * 4] =
                make_float4(o0, o1, o2, o3);
        }
    }
}

// ---------------- layer-2 aggregate (20-dim q2) + t3 assembly ----------------
// t3[n] cols 0..9 = mean_s q2_l[s] + r_l[n] + bl3 (biased trick),
//       cols 10..19 = mean_s q2_r[s] + r_r[n].  Stored bf16 (40B rows).
__global__ __launch_bounds__(256) void agg20(
    const unsigned int* __restrict__ q2b32, const int* __restrict__ cnt,
    const unsigned short* __restrict__ colbuf, const float2* __restrict__ rbuf2,
    const float* __restrict__ bl3, unsigned int* __restrict__ t3b32, int N) {
    const int lane = threadIdx.x & 63;
    const int wvi = threadIdx.x >> 6;
    const int la = lane & 15;
    const int qb = lane & 48;
    const int node = blockIdx.x * 16 + wvi * 4 + (lane >> 4);
    const bool valid = node < N;
    const int nodec = valid ? node : N - 1;
    const int deg = cnt[nodec];
    const int d = valid ? min(deg, CAP) : 0;
    const unsigned short* cb = colbuf + (size_t)nodec * CAP;

    float f0 = 0.f, f1 = 0.f;
    int nb = (d + 15) >> 4;
    for (int b = 0; b < nb; ++b) {
        int slot = b * 16 + la;
        int idx = (slot < d) ? (int)cb[slot] : N;   // N = q2 zero row
        unsigned int vv[16];
#pragma unroll
        for (int j = 0; j < 16; ++j) {
            int s = __shfl(idx, qb + j, 64);
            vv[j] = (la < 10) ? q2b32[(size_t)s * 10 + la] : 0u;
        }
#pragma unroll
        for (int j = 0; j < 16; ++j) {
            f0 += bf2f((unsigned short)(vv[j] & 0xFFFF));
            f1 += bf2f((unsigned short)(vv[j] >> 16));
        }
    }
    if (valid && la < 10) {
        float inv = 1.0f / (float)max(deg, 1);
        float2 rv = rbuf2[(size_t)node * 10 + la];
        float v0 = f0 * inv + rv.x;
        float v1 = f1 * inv + rv.y;
        if (la < 5) { v0 += bl3[2 * la]; v1 += bl3[2 * la + 1]; }
        t3b32[(size_t)node * 10 + la] =
            (unsigned int)f2bf(v0) | ((unsigned int)f2bf(v1) << 16);
    }
}

// ---------------- aggregate 10-dim (bf16 t3) + pooling ----------------
__global__ __launch_bounds__(256) void agg10_pool(
    const unsigned short* __restrict__ t3b, const int* __restrict__ cnt,
    const unsigned short* __restrict__ colbuf, const float* __restrict__ bl3,
    const int* __restrict__ batch,
    float* __restrict__ gsum, float* __restrict__ gcnt, int N) {
    __shared__ float ls[2816];
    for (int i = threadIdx.x; i < 2816; i += 256) ls[i] = 0.f;
    __syncthreads();

    const int lane = threadIdx.x & 63;
    const int wvi = threadIdx.x >> 6;
    const int la = lane & 15;
    const int qb = lane & 48;
    const int node = blockIdx.x * 16 + wvi * 4 + (lane >> 4);
    const bool valid = node < N;
    const int nodec = valid ? node : N - 1;
    const int deg = cnt[nodec];
    const int d = valid ? min(deg, CAP) : 0;
    const unsigned short* cb = colbuf + (size_t)nodec * CAP;

    float acc = 0.f;
    int nb = (d + 15) >> 4;
    for (int b = 0; b < nb; ++b) {
        int slot = b * 16 + la;
        int idx = (slot < d) ? (int)cb[slot] : N;   // N = t3 zero row
        float vv[16];
#pragma unroll
        for (int j = 0; j < 16; ++j) {
            int s = __shfl(idx, qb + j, 64);
            vv[j] = (la < 10) ? bf2f(t3b[(size_t)s * 20 + la]) : 0.f;
        }
#pragma unroll
        for (int j = 0; j < 16; ++j) acc += vv[j];
    }
    if (valid && la < 10) {
        float self = bf2f(t3b[(size_t)node * 20 + 10 + la]);
        float h = (d > 0) ? (acc / (float)deg + self) : (bl3[la] + self);
        int g = batch[node];
        atomicAdd(&ls[g * 10 + la], h);
        if (la == 0) atomicAdd(&ls[2560 + g], 1.0f);
    }
    __syncthreads();
    for (int i = threadIdx.x; i < 2816; i += 256) {
        float v = ls[i];
        if (v != 0.f) {
            if (i < 2560) atomicAdd(&gsum[i], v);
            else          atomicAdd(&gcnt[i - 2560], v);
        }
    }
}

// ---------------- mean + log_softmax ----------------
__global__ void finalize_pool(const float* __restrict__ gsum,
                              const float* __restrict__ gcnt,
                              float* __restrict__ out, int G) {
    int g = blockIdx.x * blockDim.x + threadIdx.x;
    if (g >= G) return;
    float inv = 1.0f / fmaxf(gcnt[g], 1.0f);
    float p[10];
    float m = -1e30f;
#pragma unroll
    for (int c = 0; c < 10; ++c) { p[c] = gsum[g * 10 + c] * inv; m = fmaxf(m, p[c]); }
    float s = 0.f;
#pragma unroll
    for (int c = 0; c < 10; ++c) s += expf(p[c] - m);
    float lse = logf(s);
#pragma unroll
    for (int c = 0; c < 10; ++c) out[g * 10 + c] = p[c] - m - lse;
}

extern "C" void kernel_launch(void* const* d_in, const int* in_sizes, int n_in,
                              void* d_out, int out_size, void* d_ws, size_t ws_size,
                              hipStream_t stream) {
    const float* x    = (const float*)d_in[0];
    const int*   ei   = (const int*)d_in[1];
    const int*   batch= (const int*)d_in[2];
    const float* Wl1  = (const float*)d_in[3];
    const float* bl1  = (const float*)d_in[4];
    const float* Wr1  = (const float*)d_in[5];
    const float* Wl2  = (const float*)d_in[6];
    const float* bl2  = (const float*)d_in[7];
    const float* Wr2  = (const float*)d_in[8];
    const float* Wl3  = (const float*)d_in[9];
    const float* bl3  = (const float*)d_in[10];
    const float* Wr3  = (const float*)d_in[11];
    float* out = (float*)d_out;

    const int N = in_sizes[2];
    const int E = in_sizes[1] / 2;
    const int G = out_size / 10;
    const int ablk = (E + EB - 1) / EB;
    const int nbk  = (N + 127) >> 7;

    char* ws = (char*)d_ws;
    size_t o = 0;
    float* gsum   = (float*)(ws + o); o += (size_t)G * 10 * 4;
    float* gcnt   = (float*)(ws + o); o += (size_t)G * 4;
    size_t zero_bytes = (o + 255) & ~(size_t)255;
    o = zero_bytes;
    int*            cnt    = (int*)(ws + o);            o += (size_t)N * 4;
    unsigned short* colbuf = (unsigned short*)(ws + o); o += ((size_t)N * CAP * 2 + 255) & ~(size_t)255;
    short*          Wq     = (short*)(ws + o);          o += (size_t)10240 * 2;
    float*          cbv    = (float*)(ws + o);          o += 40 * 4;
    o = (o + 255) & ~(size_t)255;
    float*          m2Mg   = (float*)(ws + o);          o += (size_t)128 * 40 * 4;      // chain intermediate
    unsigned short* mm     = (unsigned short*)(ws + o); o += (size_t)(N + 1) * 40 * 2;  // [m1|m1r] bf16 (+zero row)
    o = (o + 255) & ~(size_t)255;
    float*          bmrow  = (float*)(ws + o);          o += (size_t)N * 40 * 4;        // [bm|bmr] fp32
    unsigned short* q2b    = (unsigned short*)(ws + o); o += (size_t)(N + 1) * 20 * 2;  // q2 bf16 (+zero row)
    o = (o + 255) & ~(size_t)255;
    float*          rbuf   = (float*)(ws + o);          o += (size_t)N * 20 * 4;        // rvec fp32
    unsigned short* t3b    = (unsigned short*)(ws + o); o += (size_t)(N + 1) * 20 * 2;  // t3 bf16 (+zero row)
    o = (o + 255) & ~(size_t)255;
    unsigned int*   bedges = (unsigned int*)(ws + o);   o += (size_t)nbk * ablk * CAP * 4;
    int*            runCnt = (int*)(ws + o);            o += (size_t)ablk * nbk * 4;

    int zero_words = (int)(zero_bytes / 4);
    int zblocks = (zero_words + 255) / 256;
    prep_weights<<<ablk + 5 + zblocks, 256, 0, stream>>>(
        Wl2, Wr2, Wl3, Wr3, m2Mg,
        (int*)ws, zero_words,
        (unsigned int*)mm, (unsigned int*)q2b, (unsigned int*)t3b, N,
        ei, E, ablk, nbk, bedges, runCnt);

    prep2<<<9, 256, 0, stream>>>(Wl1, Wr1, Wl3, Wr3, bl1, bl2, m2Mg, Wq, cbv);

    int gblocks = (N + 63) / 64;
    int ablocks = (N + 15) / 16;
    fillX<<<nbk + gblocks, 256, 0, stream>>>(x, Wq, cbv, mm, bmrow, N,
                                             nbk, ablk, bedges, runCnt,
                                             cnt, colbuf);
    // collapsed layers 1-3 message aggregation (40-dim, L2-resident table)
    aggM<<<ablocks, 256, 0, stream>>>((const uint2*)mm, cnt, colbuf,
                                      bmrow, q2b, rbuf, N);
    // layer-2/3 aggregate over 20-dim q2 -> t3 (bf16)
    agg20<<<ablocks, 256, 0, stream>>>((const unsigned int*)q2b, cnt, colbuf,
                                       (const float2*)rbuf, bl3,
                                       (unsigned int*)t3b, N);
    // layer-3 aggregate + pooling
    agg10_pool<<<ablocks, 256, 0, stream>>>(t3b, cnt, colbuf, bl3, batch,
                                            gsum, gcnt, N);
    finalize_pool<<<1, 256, 0, stream>>>(gsum, gcnt, out, G);
}

// Round 6
// 175.996 us; speedup vs baseline: 1.5219x; 1.0839x over previous
//
#include <hip/hip_runtime.h>

// GraphSAGE: 3x (project -> mean-aggregate) + mean pool + log_softmax.
// R23: algebraic merge of the m1r gather into level-2.
//      t3 = S(q2) + S(m1r) + bmr = S(q2 + m1r) + bmr, and
//      z[s] = q2[s] + m1r[s] = S(m1)[s] + x[s](B+C) + c1  -> single combined
//      self-matrix. Per-edge gather bytes 140 -> 100 (aggM 80->40), mm table
//      4MB -> 2MB, rbuf (8MB fp32) eliminated, fillX 5 -> 4 MFMA tiles
//      (P = [A | B+C | D], 60 cols). agg10_pool loads widened 2B -> 4B.
//      Pipeline: prep (scatter + stage1/2) -> prep2 (P pack + cbv)
//        -> fillX -> aggM(40B) -> agg20(40B) -> agg10_pool(20B) -> finalize.

#define CAP 48
#define EB 4096

typedef __attribute__((ext_vector_type(8))) short short8;
typedef __attribute__((ext_vector_type(4))) float floatx4;

static __device__ __forceinline__ unsigned short f2bf(float f) {
    unsigned int u = __float_as_uint(f);
    u += 0x7FFFu + ((u >> 16) & 1u);
    return (unsigned short)(u >> 16);
}
static __device__ __forceinline__ float bf2f(unsigned short b) {
    return __uint_as_float(((unsigned int)b) << 16);
}

// ---------------- prep: bucket scatter + chain stage1/2 + zeroing ----
// Chain (4 blocks, rb<4): wtT[f][c] (128x20, LDS); block rb computes m2M rows
// j in [rb*32, rb*32+32): m2Mg[j][cc] = sum_f W2half[j][f] * wtT[f][c20].
__global__ void prep_weights(const float* __restrict__ Wl2, const float* __restrict__ Wr2,
                             const float* __restrict__ Wl3, const float* __restrict__ Wr3,
                             float* __restrict__ m2Mg,
                             int* __restrict__ zero_base, int zero_words,
                             unsigned int* __restrict__ mmz, unsigned int* __restrict__ zb32,
                             unsigned int* __restrict__ t3b32, int N,
                             const int* __restrict__ ei, int E, int ablk, int nbk,
                             unsigned int* __restrict__ bedges, int* __restrict__ runCnt) {
    __shared__ int hist[512];
    __shared__ float wtT_s[128 * 20];
    if (blockIdx.x < (unsigned)ablk) {
        for (int i = threadIdx.x; i < nbk; i += 256) hist[i] = 0;
        __syncthreads();
        int e0 = blockIdx.x * EB + threadIdx.x;
        unsigned int pk[16];
        int bk[16], loc[16];
#pragma unroll
        for (int k = 0; k < 16; ++k) {
            int e = e0 + k * 256;
            if (e < E) {
                int src = ei[e];
                int dst = ei[E + e];
                bk[k] = dst >> 7;
                pk[k] = ((unsigned int)(dst & 127) << 16) | (unsigned int)src;
                loc[k] = atomicAdd(&hist[bk[k]], 1);    // LDS atomic
            } else bk[k] = -1;
        }
        __syncthreads();
        for (int i = threadIdx.x; i < nbk; i += 256)
            runCnt[(size_t)blockIdx.x * nbk + i] = hist[i];
#pragma unroll
        for (int k = 0; k < 16; ++k)
            if (bk[k] >= 0 && loc[k] < CAP)
                bedges[((size_t)bk[k] * ablk + blockIdx.x) * CAP + loc[k]] = pk[k];
        return;
    }
    int rb = blockIdx.x - ablk;
    if (rb < 4) {
        const int tid = threadIdx.x;
        // stage 1: wtT[f][c] (natural layout of Wl3/Wr3)
        for (int i = tid; i < 2560; i += 256) {
            int f = i / 20, c = i - f * 20;
            wtT_s[i] = (c < 10) ? Wl3[f * 10 + c] : Wr3[f * 10 + (c - 10)];
        }
        __syncthreads();
        // stage 2: 32 m2M rows for this block, 8 threads per row (5 cols each)
        int jl = tid >> 3;             // 0..31
        int cg = tid & 7;              // 0..7
        int j = rb * 32 + jl;
        const float* w2row = ((cg < 4) ? Wl2 : Wr2) + (size_t)j * 128;
        int c20 = (cg & 3) * 5;        // column base within wtT's 20
        float acc[5] = {0.f, 0.f, 0.f, 0.f, 0.f};
        for (int f4 = 0; f4 < 32; ++f4) {
            float4 wv = *(const float4*)&w2row[f4 * 4];
#pragma unroll
            for (int e = 0; e < 4; ++e) {
                float w = (e == 0) ? wv.x : (e == 1) ? wv.y : (e == 2) ? wv.z : wv.w;
                const float* wt = &wtT_s[(f4 * 4 + e) * 20 + c20];
#pragma unroll
                for (int i = 0; i < 5; ++i) acc[i] += w * wt[i];
            }
        }
        int cc = (cg >> 2) * 20 + c20;
#pragma unroll
        for (int i = 0; i < 5; ++i) m2Mg[j * 40 + cc + i] = acc[i];
        return;
    }
    if (rb == 4) {
        // zero rows: mm (10 uints now), z (10), t3 (10)
        if (threadIdx.x < 10) mmz[(size_t)N * 10 + threadIdx.x] = 0;
        if (threadIdx.x >= 32 && threadIdx.x < 42)
            zb32[(size_t)N * 10 + (threadIdx.x - 32)] = 0;
        if (threadIdx.x >= 64 && threadIdx.x < 74)
            t3b32[(size_t)N * 10 + (threadIdx.x - 64)] = 0;
        return;
    }
    int i = (rb - 5) * 256 + threadIdx.x;
    if (i < zero_words) zero_base[i] = 0;
}

// ---------------- prep2: P = [A | B+C | D] (60 cols) pack + cbv --------------
// A = Wl1@m2, B = Wr1@m2, C = Wl1@m2r, D = Wr1@m2r.
// Blocks 0..3: 32 k-rows each; thread (kl, cg): cg<4 uses Wl1[k] (A cols +
// C partials via LDS), cg>=4 uses Wr1[k] (B+C cols, D cols).
// Block 4: cbv[0..19] = bl1@m2 ; cbv[20..39] = bl1@m2r + bl2@wt; zero f60..63.
__global__ __launch_bounds__(256) void prep2(
    const float* __restrict__ Wl1, const float* __restrict__ Wr1,
    const float* __restrict__ Wl3, const float* __restrict__ Wr3,
    const float* __restrict__ bl1, const float* __restrict__ bl2,
    const float* __restrict__ m2Mg, short* __restrict__ Wq,
    float* __restrict__ cbv) {
    __shared__ float m2s[128 * 40];
    __shared__ float cL[32][20];
    const int tid = threadIdx.x;
    if (blockIdx.x == 4) {
        // zero unused weight columns f=60..63 (outputs discarded but keep clean)
        for (int i = tid; i < 512; i += 256) {
            int k = i >> 2, f = 60 + (i & 3);
            int ks = k >> 5, rem = k & 31, qq = rem >> 3, jj = rem & 7;
            int mi = f >> 4, m = f & 15, l = qq * 16 + m;
            Wq[(((mi * 4 + ks) * 64) + l) * 8 + jj] = 0;
        }
        if (tid < 40) {
            float s = 0.f;
            if (tid < 20) {
                for (int k = 0; k < 128; ++k) s += bl1[k] * m2Mg[k * 40 + tid];
            } else {
                int c = tid - 20;
                for (int k = 0; k < 128; ++k) s += bl1[k] * m2Mg[k * 40 + 20 + c];
                for (int f = 0; f < 128; ++f) {
                    float wt = (c < 10) ? Wl3[f * 10 + c] : Wr3[f * 10 + (c - 10)];
                    s += bl2[f] * wt;
                }
            }
            cbv[tid] = s;
        }
        return;
    }
    for (int i = tid; i < 5120; i += 256) m2s[i] = m2Mg[i];
    __syncthreads();
    int kl = tid >> 3;                 // 0..31
    int cg = tid & 7;                  // 0..7
    int k = blockIdx.x * 32 + kl;      // 0..127
    int c0 = (cg & 3) * 5;
    bool left = (cg < 4);
    const float* wrow = (left ? Wl1 : Wr1) + (size_t)k * 128;
    float accM[5] = {0.f, 0.f, 0.f, 0.f, 0.f};  // row @ m2  cols c0..c0+4
    float accR[5] = {0.f, 0.f, 0.f, 0.f, 0.f};  // row @ m2r cols c0..c0+4
    for (int j4 = 0; j4 < 32; ++j4) {
        float4 wv = *(const float4*)&wrow[j4 * 4];
#pragma unroll
        for (int e = 0; e < 4; ++e) {
            float w = (e == 0) ? wv.x : (e == 1) ? wv.y : (e == 2) ? wv.z : wv.w;
            const float* mr = &m2s[(j4 * 4 + e) * 40];
#pragma unroll
            for (int i = 0; i < 5; ++i) {
                accM[i] += w * mr[c0 + i];
                accR[i] += w * mr[20 + c0 + i];
            }
        }
    }
    if (left) {
#pragma unroll
        for (int i = 0; i < 5; ++i) cL[kl][c0 + i] = accR[i];   // C partials
    }
    __syncthreads();
    int ks = k >> 5, rem = k & 31, qq = rem >> 3, jj = rem & 7;
#pragma unroll
    for (int i = 0; i < 5; ++i) {
        if (left) {
            int f = c0 + i;                       // A
            int mi = f >> 4, m = f & 15, l = qq * 16 + m;
            Wq[(((mi * 4 + ks) * 64) + l) * 8 + jj] = (short)f2bf(accM[i]);
        } else {
            int f = 20 + c0 + i;                  // B + C
            int mi = f >> 4, m = f & 15, l = qq * 16 + m;
            Wq[(((mi * 4 + ks) * 64) + l) * 8 + jj] =
                (short)f2bf(accM[i] + cL[kl][c0 + i]);
            int f2 = 40 + c0 + i;                 // D
            int mi2 = f2 >> 4, m2 = f2 & 15, l2 = qq * 16 + m2;
            Wq[(((mi2 * 4 + ks) * 64) + l2) * 8 + jj] = (short)f2bf(accR[i]);
        }
    }
}

// ---------------- fillX: phase-B CSR fill + dense x @ [A|B+C|D] --------------
// 64 nodes/block, wave w owns node node0+w*16+m; 4 m-tiles (64 outputs,
// f60..63 discarded). f<20 -> mm (m1, bf16 40B rows);
// f in [20,60) -> bmrow [bmplus(20)|bmr2(20)] fp32 (+cbv).
__global__ __launch_bounds__(256) void fillX(
    const float* __restrict__ x, const short* __restrict__ Wq,
    const float* __restrict__ cbv, unsigned short* __restrict__ mm,
    float* __restrict__ bmrow, int N, int nbk, int ablk,
    const unsigned int* __restrict__ bedges, const int* __restrict__ runCnt,
    int* __restrict__ cnt, unsigned short* __restrict__ colbuf) {
    __shared__ unsigned short As[64 * 136];
    __shared__ int lcnt[128];
    if (blockIdx.x >= (unsigned)nbk) {
        int blk = blockIdx.x - nbk;
        int node0 = blk * 64;
#pragma unroll
        for (int c = 0; c < 8; ++c) {
            int idx = c * 256 + threadIdx.x;
            int r = idx >> 5;
            int c4 = idx & 31;
            int row = node0 + r;
            float4 v = make_float4(0.f, 0.f, 0.f, 0.f);
            if (row < N) v = *(const float4*)&x[(size_t)row * 128 + c4 * 4];
            ushort4 p;
            p.x = f2bf(v.x); p.y = f2bf(v.y); p.z = f2bf(v.z); p.w = f2bf(v.w);
            *(ushort4*)&As[r * 136 + c4 * 4] = p;
        }
        __syncthreads();

        const int w = threadIdx.x >> 6;
        const int lane = threadIdx.x & 63;
        const int q = lane >> 4;
        const int m = lane & 15;

        floatx4 acc[4] = {};
#pragma unroll
        for (int s = 0; s < 4; ++s) {
            short8 bfrag = *(const short8*)&As[(w * 16 + m) * 136 + s * 32 + q * 8];
#pragma unroll
            for (int mi = 0; mi < 4; ++mi) {
                short8 wf = *(const short8*)&Wq[((mi * 4 + s) * 64 + lane) * 8];
                acc[mi] = __builtin_amdgcn_mfma_f32_16x16x32_bf16(
                    wf, bfrag, acc[mi], 0, 0, 0);
            }
        }
        int node = node0 + w * 16 + m;
        if (node < N) {
#pragma unroll
            for (int mi = 0; mi < 4; ++mi) {
                int f0 = mi * 16 + q * 4;
                floatx4 a = acc[mi];
                if (f0 < 20) {
                    ushort4 p;
                    p.x = f2bf(a[0]); p.y = f2bf(a[1]);
                    p.z = f2bf(a[2]); p.w = f2bf(a[3]);
                    *(ushort4*)&mm[(size_t)node * 20 + f0] = p;
                } else if (f0 < 60) {
                    float4 cb = *(const float4*)&cbv[f0 - 20];
                    float4 o = make_float4(a[0] + cb.x, a[1] + cb.y,
                                           a[2] + cb.z, a[3] + cb.w);
                    *(float4*)&bmrow[(size_t)node * 40 + (f0 - 20)] = o;
                }
            }
        }
    } else {
        int b = blockIdx.x;
        if (threadIdx.x < 128) lcnt[threadIdx.x] = 0;
        __syncthreads();
        for (int blk = threadIdx.x; blk < ablk; blk += 256) {
            int c = runCnt[(size_t)blk * nbk + b];
            c = min(c, CAP);
            size_t ebase = ((size_t)b * ablk + blk) * CAP;
            for (int i = 0; i < c; ++i) {
                unsigned int pk = bedges[ebase + i];
                int dl = pk >> 16;
                int slot = atomicAdd(&lcnt[dl], 1);    // LDS atomic
                if (slot < CAP)
                    colbuf[(size_t)(b * 128 + dl) * CAP + slot] =
                        (unsigned short)(pk & 0xFFFFu);
            }
        }
        __syncthreads();
        int node = b * 128 + threadIdx.x;
        if (threadIdx.x < 128 && node < N) cnt[node] = lcnt[threadIdx.x];
    }
}

// ---------------- aggM: 20-dim gather over mm (40B rows, L2-resident) --------
// z[n] = mean_s m1[s] + bmplus[n]   (bf16 out; bmplus = x(B+C)+c1)
__global__ __launch_bounds__(256) void aggM(
    const unsigned int* __restrict__ mm32, const int* __restrict__ cnt,
    const unsigned short* __restrict__ colbuf, const float2* __restrict__ bmrow2,
    unsigned int* __restrict__ zb32, int N) {
    const int lane = threadIdx.x & 63;
    const int wvi = threadIdx.x >> 6;
    const int la = lane & 15;
    const int qb = lane & 48;
    const int node = blockIdx.x * 16 + wvi * 4 + (lane >> 4);
    const bool valid = node < N;
    const int nodec = valid ? node : N - 1;
    const int deg = cnt[nodec];
    const int d = valid ? min(deg, CAP) : 0;
    const unsigned short* cb = colbuf + (size_t)nodec * CAP;

    float f0 = 0.f, f1 = 0.f;
    int nb = (d + 15) >> 4;
    for (int b = 0; b < nb; ++b) {
        int slot = b * 16 + la;
        int idx = (slot < d) ? (int)cb[slot] : N;   // N = mm zero row
        unsigned int vv[16];
#pragma unroll
        for (int j = 0; j < 16; ++j) {
            int s = __shfl(idx, qb + j, 64);
            vv[j] = (la < 10) ? mm32[(size_t)s * 10 + la] : 0u;
        }
#pragma unroll
        for (int j = 0; j < 16; ++j) {
            f0 += bf2f((unsigned short)(vv[j] & 0xFFFF));
            f1 += bf2f((unsigned short)(vv[j] >> 16));
        }
    }
    if (valid && la < 10) {
        float inv = 1.0f / (float)max(deg, 1);
        float2 bp = bmrow2[(size_t)node * 20 + la];   // bmplus dims 2la,2la+1
        float v0 = f0 * inv + bp.x;
        float v1 = f1 * inv + bp.y;
        zb32[(size_t)node * 10 + la] =
            (unsigned int)f2bf(v0) | ((unsigned int)f2bf(v1) << 16);
    }
}

// ---------------- agg20: gather z -> t3 assembly ----------------
// t3[n] cols 0..9 = mean_s z_l[s] + bmr2_l[n] + bl3 (biased trick),
//       cols 10..19 = mean_s z_r[s] + bmr2_r[n].  Stored bf16 (40B rows).
__global__ __launch_bounds__(256) void agg20(
    const unsigned int* __restrict__ zb32, const int* __restrict__ cnt,
    const unsigned short* __restrict__ colbuf, const float2* __restrict__ bmrow2,
    const float* __restrict__ bl3, unsigned int* __restrict__ t3b32, int N) {
    const int lane = threadIdx.x & 63;
    const int wvi = threadIdx.x >> 6;
    const int la = lane & 15;
    const int qb = lane & 48;
    const int node = blockIdx.x * 16 + wvi * 4 + (lane >> 4);
    const bool valid = node < N;
    const int nodec = valid ? node : N - 1;
    const int deg = cnt[nodec];
    const int d = valid ? min(deg, CAP) : 0;
    const unsigned short* cb = colbuf + (size_t)nodec * CAP;

    float f0 = 0.f, f1 = 0.f;
    int nb = (d + 15) >> 4;
    for (int b = 0; b < nb; ++b) {
        int slot = b * 16 + la;
        int idx = (slot < d) ? (int)cb[slot] : N;   // N = z zero row
        unsigned int vv[16];
#pragma unroll
        for (int j = 0; j < 16; ++j) {
            int s = __shfl(idx, qb + j, 64);
            vv[j] = (la < 10) ? zb32[(size_t)s * 10 + la] : 0u;
        }
#pragma unroll
        for (int j = 0; j < 16; ++j) {
            f0 += bf2f((unsigned short)(vv[j] & 0xFFFF));
            f1 += bf2f((unsigned short)(vv[j] >> 16));
        }
    }
    if (valid && la < 10) {
        float inv = 1.0f / (float)max(deg, 1);
        float2 rv = bmrow2[(size_t)node * 20 + 10 + la];  // bmr2 dims 2la,2la+1
        float v0 = f0 * inv + rv.x;
        float v1 = f1 * inv + rv.y;
        if (la < 5) { v0 += bl3[2 * la]; v1 += bl3[2 * la + 1]; }
        t3b32[(size_t)node * 10 + la] =
            (unsigned int)f2bf(v0) | ((unsigned int)f2bf(v1) << 16);
    }
}

// ---------------- aggregate 10-dim (bf16 t3, 4B loads) + pooling ----------------
__global__ __launch_bounds__(256) void agg10_pool(
    const unsigned int* __restrict__ t3b32, const int* __restrict__ cnt,
    const unsigned short* __restrict__ colbuf, const float* __restrict__ bl3,
    const int* __restrict__ batch,
    float* __restrict__ gsum, float* __restrict__ gcnt, int N) {
    __shared__ float ls[2816];
    for (int i = threadIdx.x; i < 2816; i += 256) ls[i] = 0.f;
    __syncthreads();

    const int lane = threadIdx.x & 63;
    const int wvi = threadIdx.x >> 6;
    const int la = lane & 15;
    const int qb = lane & 48;
    const int node = blockIdx.x * 16 + wvi * 4 + (lane >> 4);
    const bool valid = node < N;
    const int nodec = valid ? node : N - 1;
    const int deg = cnt[nodec];
    const int d = valid ? min(deg, CAP) : 0;
    const unsigned short* cb = colbuf + (size_t)nodec * CAP;

    float acc0 = 0.f, acc1 = 0.f;          // dims 2la, 2la+1 (la < 5)
    int nb = (d + 15) >> 4;
    for (int b = 0; b < nb; ++b) {
        int slot = b * 16 + la;
        int idx = (slot < d) ? (int)cb[slot] : N;   // N = t3 zero row
        unsigned int vv[16];
#pragma unroll
        for (int j = 0; j < 16; ++j) {
            int s = __shfl(idx, qb + j, 64);
            vv[j] = (la < 5) ? t3b32[(size_t)s * 10 + la] : 0u;
        }
#pragma unroll
        for (int j = 0; j < 16; ++j) {
            acc0 += bf2f((unsigned short)(vv[j] & 0xFFFF));
            acc1 += bf2f((unsigned short)(vv[j] >> 16));
        }
    }
    if (valid && la < 5) {
        unsigned int sv = t3b32[(size_t)node * 10 + 5 + la];   // t3_r dims
        float self0 = bf2f((unsigned short)(sv & 0xFFFF));
        float self1 = bf2f((unsigned short)(sv >> 16));
        float h0 = (d > 0) ? (acc0 / (float)deg + self0) : (bl3[2 * la] + self0);
        float h1 = (d > 0) ? (acc1 / (float)deg + self1) : (bl3[2 * la + 1] + self1);
        int g = batch[node];
        atomicAdd(&ls[g * 10 + 2 * la], h0);
        atomicAdd(&ls[g * 10 + 2 * la + 1], h1);
        if (la == 0) atomicAdd(&ls[2560 + g], 1.0f);
    }
    __syncthreads();
    for (int i = threadIdx.x; i < 2816; i += 256) {
        float v = ls[i];
        if (v != 0.f) {
            if (i < 2560) atomicAdd(&gsum[i], v);
            else          atomicAdd(&gcnt[i - 2560], v);
        }
    }
}

// ---------------- mean + log_softmax ----------------
__global__ void finalize_pool(const float* __restrict__ gsum,
                              const float* __restrict__ gcnt,
                              float* __restrict__ out, int G) {
    int g = blockIdx.x * blockDim.x + threadIdx.x;
    if (g >= G) return;
    float inv = 1.0f / fmaxf(gcnt[g], 1.0f);
    float p[10];
    float m = -1e30f;
#pragma unroll
    for (int c = 0; c < 10; ++c) { p[c] = gsum[g * 10 + c] * inv; m = fmaxf(m, p[c]); }
    float s = 0.f;
#pragma unroll
    for (int c = 0; c < 10; ++c) s += expf(p[c] - m);
    float lse = logf(s);
#pragma unroll
    for (int c = 0; c < 10; ++c) out[g * 10 + c] = p[c] - m - lse;
}

extern "C" void kernel_launch(void* const* d_in, const int* in_sizes, int n_in,
                              void* d_out, int out_size, void* d_ws, size_t ws_size,
                              hipStream_t stream) {
    const float* x    = (const float*)d_in[0];
    const int*   ei   = (const int*)d_in[1];
    const int*   batch= (const int*)d_in[2];
    const float* Wl1  = (const float*)d_in[3];
    const float* bl1  = (const float*)d_in[4];
    const float* Wr1  = (const float*)d_in[5];
    const float* Wl2  = (const float*)d_in[6];
    const float* bl2  = (const float*)d_in[7];
    const float* Wr2  = (const float*)d_in[8];
    const float* Wl3  = (const float*)d_in[9];
    const float* bl3  = (const float*)d_in[10];
    const float* Wr3  = (const float*)d_in[11];
    float* out = (float*)d_out;

    const int N = in_sizes[2];
    const int E = in_sizes[1] / 2;
    const int G = out_size / 10;
    const int ablk = (E + EB - 1) / EB;
    const int nbk  = (N + 127) >> 7;

    char* ws = (char*)d_ws;
    size_t o = 0;
    float* gsum   = (float*)(ws + o); o += (size_t)G * 10 * 4;
    float* gcnt   = (float*)(ws + o); o += (size_t)G * 4;
    size_t zero_bytes = (o + 255) & ~(size_t)255;
    o = zero_bytes;
    int*            cnt    = (int*)(ws + o);            o += (size_t)N * 4;
    unsigned short* colbuf = (unsigned short*)(ws + o); o += ((size_t)N * CAP * 2 + 255) & ~(size_t)255;
    short*          Wq     = (short*)(ws + o);          o += (size_t)8192 * 2;
    float*          cbv    = (float*)(ws + o);          o += 40 * 4;
    o = (o + 255) & ~(size_t)255;
    float*          m2Mg   = (float*)(ws + o);          o += (size_t)128 * 40 * 4;      // chain intermediate
    unsigned short* mm     = (unsigned short*)(ws + o); o += (size_t)(N + 1) * 20 * 2;  // m1 bf16 40B rows (+zero)
    o = (o + 255) & ~(size_t)255;
    float*          bmrow  = (float*)(ws + o);          o += (size_t)N * 40 * 4;        // [bmplus|bmr2] fp32
    unsigned short* zb     = (unsigned short*)(ws + o); o += (size_t)(N + 1) * 20 * 2;  // z bf16 (+zero row)
    o = (o + 255) & ~(size_t)255;
    unsigned short* t3b    = (unsigned short*)(ws + o); o += (size_t)(N + 1) * 20 * 2;  // t3 bf16 (+zero row)
    o = (o + 255) & ~(size_t)255;
    unsigned int*   bedges = (unsigned int*)(ws + o);   o += (size_t)nbk * ablk * CAP * 4;
    int*            runCnt = (int*)(ws + o);            o += (size_t)ablk * nbk * 4;

    int zero_words = (int)(zero_bytes / 4);
    int zblocks = (zero_words + 255) / 256;
    prep_weights<<<ablk + 5 + zblocks, 256, 0, stream>>>(
        Wl2, Wr2, Wl3, Wr3, m2Mg,
        (int*)ws, zero_words,
        (unsigned int*)mm, (unsigned int*)zb, (unsigned int*)t3b, N,
        ei, E, ablk, nbk, bedges, runCnt);

    prep2<<<5, 256, 0, stream>>>(Wl1, Wr1, Wl3, Wr3, bl1, bl2, m2Mg, Wq, cbv);

    int gblocks = (N + 63) / 64;
    int ablocks = (N + 15) / 16;
    fillX<<<nbk + gblocks, 256, 0, stream>>>(x, Wq, cbv, mm, bmrow, N,
                                             nbk, ablk, bedges, runCnt,
                                             cnt, colbuf);
    // level-1: z = S(m1) + x(B+C) + c1   (40B/edge gather)
    aggM<<<ablocks, 256, 0, stream>>>((const unsigned int*)mm, cnt, colbuf,
                                      (const float2*)bmrow,
                                      (unsigned int*)zb, N);
    // level-2: t3 = S(z) + bmr2 (+bl3 trick)   (40B/edge gather)
    agg20<<<ablocks, 256, 0, stream>>>((const unsigned int*)zb, cnt, colbuf,
                                       (const float2*)bmrow, bl3,
                                       (unsigned int*)t3b, N);
    // level-3: aggregate + pooling   (20B/edge gather)
    agg10_pool<<<ablocks, 256, 0, stream>>>((const unsigned int*)t3b, cnt, colbuf,
                                            bl3, batch, gsum, gcnt, N);
    finalize_pool<<<1, 256, 0, stream>>>(gsum, gcnt, out, G);
}